// Round 14
// baseline (105.218 us; speedup 1.0000x reference)
//
#include <hip/hip_runtime.h>
#include <hip/hip_bf16.h>

#define N_IN 128
#define N_OUT 64
#define KNBR 32
#define SLICE_CH 16
#define MB_NODES 32  // nodes per median block (4 waves x 8 nodes)

typedef __attribute__((ext_vector_type(4))) float fx4;
typedef __attribute__((ext_vector_type(2))) float fx2;
typedef __attribute__((ext_vector_type(8))) short bh8;

// ---------- compile-time Batcher odd-even mergesort network for 16 ----------
struct Net {
  int a[64];
  int b[64];
  int n;
};

constexpr Net make_batcher16() {
  Net net{};
  net.n = 0;
  const int n = 16;
  for (int p = 1; p < n; p <<= 1)
    for (int k = p; k >= 1; k >>= 1)
      for (int j = k % p; j + k < n; j += 2 * k)
        for (int i = 0; i < k && i + j + k < n; ++i)
          if ((i + j) / (2 * p) == (i + j + k) / (2 * p)) {
            net.a[net.n] = i + j;
            net.b[net.n] = i + j + k;
            net.n++;
          }
  return net;
}

constexpr Net NET16 = make_batcher16();
static_assert(NET16.n == 63, "batcher16 comparator count must be 63");

// packed 16-bit unsigned min/max (VOP3P) — one instr covers 2 channels
__device__ __forceinline__ unsigned pkmin(unsigned a, unsigned b) {
  unsigned r;
  asm("v_pk_min_u16 %0, %1, %2" : "=v"(r) : "v"(a), "v"(b));
  return r;
}
__device__ __forceinline__ unsigned pkmax(unsigned a, unsigned b) {
  unsigned r;
  asm("v_pk_max_u16 %0, %1, %2" : "=v"(r) : "v"(a), "v"(b));
  return r;
}
__device__ __forceinline__ void casp(unsigned& x, unsigned& y) {
  unsigned lo = pkmin(x, y);
  unsigned hi = pkmax(x, y);
  x = lo;
  y = hi;
}

__device__ __forceinline__ unsigned short bf_bits(float f) {
  union { __hip_bfloat16 b; unsigned short u; } cv;
  cv.b = __float2bfloat16(f);  // RNE
  return cv.u;
}

__device__ __forceinline__ unsigned cvtpk(float a, float b) {
  unsigned r;
  asm("v_cvt_pk_bf16_f32 %0, %1, %2" : "=v"(r) : "v"(a), "v"(b));
  return r;
}

// ---------------- kernel 0: normalize edges to int32 in workspace ----------
__global__ __launch_bounds__(256) void normalize_edges(
    const void* __restrict__ ei, int* __restrict__ e32c, long long E) {
  const int* e32 = (const int*)ei;
  const long long* e64 = (const long long*)ei;
  // int64 little-endian => high words (odd int32 slots) of first 8 elems are 0
  bool is64 = (e32[1] == 0) && (e32[3] == 0) && (e32[5] == 0) &&
              (e32[7] == 0) && (e32[9] == 0) && (e32[11] == 0) &&
              (e32[13] == 0) && (e32[15] == 0);
  const long long i0 = (long long)blockIdx.x * blockDim.x + threadIdx.x;
  const long long stride = (long long)gridDim.x * blockDim.x;
  for (long long i = i0; i < E; i += stride) {
    int v;
    if (is64) {
      v = (int)__builtin_nontemporal_load(&e64[i]);
    } else {
      v = __builtin_nontemporal_load(&e32[i]);
    }
    __builtin_nontemporal_store(v, &e32c[i]);
  }
}

// ---------------- kernel 1: h = x @ W via MFMA, SLICE-MAJOR bf16 keys -------
// h layout: [4 slices][n][16 ch] u16. wave = 16-row tile x 64 cols.
// A/B frags share the same (lane-group,elem)->k mapping (permutation cancels).
// C/D layout: col=lane&15, row=(lane>>4)*4+reg. slice = ct.
__device__ __forceinline__ void tile_compute_store(
    const fx4* xp, const bh8 bf[4][4], unsigned short* __restrict__ h,
    int t, int n, int l4, int g) {
  fx4 acc[4];
#pragma unroll
  for (int ct = 0; ct < 4; ++ct) acc[ct] = fx4{0.f, 0.f, 0.f, 0.f};

#pragma unroll
  for (int kc = 0; kc < 4; ++kc) {
    union { unsigned u[4]; bh8 s; } av;
    av.u[0] = cvtpk(xp[kc * 2 + 0].x, xp[kc * 2 + 0].y);
    av.u[1] = cvtpk(xp[kc * 2 + 0].z, xp[kc * 2 + 0].w);
    av.u[2] = cvtpk(xp[kc * 2 + 1].x, xp[kc * 2 + 1].y);
    av.u[3] = cvtpk(xp[kc * 2 + 1].z, xp[kc * 2 + 1].w);
#pragma unroll
    for (int ct = 0; ct < 4; ++ct)
      acc[ct] = __builtin_amdgcn_mfma_f32_16x16x32_bf16(av.s, bf[kc][ct],
                                                        acc[ct], 0, 0, 0);
  }

#pragma unroll
  for (int ct = 0; ct < 4; ++ct)
#pragma unroll
    for (int r = 0; r < 4; ++r) {
      int row = t * 16 + g * 4 + r;
      if (row < n) {
        unsigned short ub = bf_bits(acc[ct][r]);
        unsigned short key = (ub & 0x8000) ? (unsigned short)(~ub)
                                           : (unsigned short)(ub | 0x8000);
        h[((size_t)ct * n + row) * SLICE_CH + l4] = key;  // slice-major
      }
    }
}

__device__ __forceinline__ void tile_load(fx4* xp, const float* __restrict__ x,
                                          int t, int n, int l4, int g) {
  int row = t * 16 + l4;
  if (row >= n) row = n - 1;  // safe clamp (store guard discards)
  const float* xr = x + (size_t)row * N_IN + g * 8;
#pragma unroll
  for (int kc = 0; kc < 4; ++kc) {
    xp[kc * 2 + 0] = *(const fx4*)(xr + kc * 32);
    xp[kc * 2 + 1] = *(const fx4*)(xr + kc * 32 + 4);
  }
}

__global__ __launch_bounds__(320) void gemm_kernel(
    const float* __restrict__ x, const float* __restrict__ W,
    unsigned short* __restrict__ h, int n) {
  const int lane = threadIdx.x & 63;
  const int l4 = lane & 15;
  const int g = lane >> 4;
  const int wid = blockIdx.x * 5 + (threadIdx.x >> 6);
  const int nw = gridDim.x * 5;
  const int ntiles = (n + 15) >> 4;
  if (wid >= ntiles) return;

  const int t0 = wid;
  const int t1 = wid + nw;

  fx4 xa[8], xb[8];
  tile_load(xa, x, t0, n, l4, g);
  const bool has2 = (t1 < ntiles);
  if (has2) tile_load(xb, x, t1, n, l4, g);

  bh8 bf[4][4];
#pragma unroll
  for (int kc = 0; kc < 4; ++kc)
#pragma unroll
    for (int ct = 0; ct < 4; ++ct) {
      float f[8];
#pragma unroll
      for (int j = 0; j < 8; ++j)
        f[j] = W[(size_t)(kc * 32 + g * 8 + j) * N_OUT + ct * 16 + l4];
      union { unsigned u[4]; bh8 s; } cv;
      cv.u[0] = cvtpk(f[0], f[1]);
      cv.u[1] = cvtpk(f[2], f[3]);
      cv.u[2] = cvtpk(f[4], f[5]);
      cv.u[3] = cvtpk(f[6], f[7]);
      bf[kc][ct] = cv.s;
    }

  tile_compute_store(xa, bf, h, t0, n, l4, g);
  if (has2) tile_compute_store(xb, bf, h, t1, n, l4, g);

  for (int t = t1 + nw; t < ntiles; t += nw) {
    tile_load(xa, x, t, n, l4, g);
    tile_compute_store(xa, bf, h, t, n, l4, g);
  }
}

// -------- kernel 2: XCD-sliced median, whole-line gather shape --------------
// slice = (bid&7)>>1: each XCD pair owns one 3.2 MB 16-ch slice (L2-resident;
// r9-verified FETCH collapse). wave = 8 nodes x 8 lanes x 2ch: one gather
// instr per j = 8 rows x 32 B, EVERY byte consumed (r9's failure was 16
// half-used lines/instr). Per-lane packed-u16 sort (exact median of 33).
__global__ __launch_bounds__(256) void median_kernel(
    const unsigned short* __restrict__ hs, const int* __restrict__ e32c,
    const float* __restrict__ bias, float* __restrict__ out, int n) {
  __shared__ int sidx[MB_NODES * 33];  // [node][nbr], stride 33 (pad)

  const int bid = blockIdx.x;
  const int slice = (bid & 7) >> 1;
  const int sub = bid & 1;
  const int chunk = bid >> 3;
  const int node0 = (chunk * 2 + sub) * MB_NODES;
  if (node0 >= n) return;  // block-uniform

  const int t = threadIdx.x;
  // stage 32 nodes x 32 neighbor indices (coalesced, nt) + self loop
  const long long ebase = (long long)node0 * KNBR;
#pragma unroll
  for (int k = 0; k < 4; ++k) {
    int p = k * 256 + t;  // 0..1023
    int nb = p >> 5;
    int v = 0;
    if (node0 + nb < n) v = __builtin_nontemporal_load(&e32c[ebase + p]);
    sidx[nb * 33 + (p & 31)] = v;
  }
  if (t < MB_NODES) {
    int nd = node0 + t;
    sidx[t * 33 + 32] = (nd < n) ? nd : 0;
  }
  __syncthreads();

  const int lane = t & 63;
  const int wslot = t >> 6;
  const int nb = wslot * 8 + (lane >> 3);  // node within block
  const int node = node0 + nb;
  const int sub8 = lane & 7;  // lane within node-octet: channels sub8*2..+1
  const bool active = (node < n);

  const unsigned char* hbase =
      (const unsigned char*)hs + (size_t)slice * ((size_t)n * 32u);
  const unsigned laneoff = (unsigned)sub8 * 4u;

  unsigned v[33];
#pragma unroll
  for (int j = 0; j < 33; ++j) {
    unsigned s = (unsigned)sidx[nb * 33 + j];  // 8-lane broadcast LDS read
    v[j] = *(const unsigned*)(hbase + ((size_t)s * 32u + laneoff));
  }

  // sort the two 16-element halves (packed: both channels at once)
#pragma unroll
  for (int i = 0; i < NET16.n; ++i) casp(v[NET16.a[i]], v[NET16.b[i]]);
#pragma unroll
  for (int i = 0; i < NET16.n; ++i) casp(v[16 + NET16.a[i]], v[16 + NET16.b[i]]);

  // ranks 15,16 of merged 32 via crossing min/max
  unsigned r15 = 0u;
  unsigned r16 = 0xFFFFFFFFu;
#pragma unroll
  for (int i = 0; i < 16; ++i) {
    unsigned lo = pkmin(v[i], v[16 + 15 - i]);
    unsigned hi = pkmax(v[i], v[16 + 15 - i]);
    r15 = pkmax(r15, lo);
    r16 = pkmin(r16, hi);
  }

  // median of 33 = clamp(self, r15, r16) in key domain (exact)
  unsigned med = pkmax(r15, pkmin(v[32], r16));

  if (active) {
    // inverse transform (per 16-bit half): t>=0x8000 ? t^0x8000 : ~t
    unsigned sg = (med >> 15) & 0x00010001u;
    unsigned u = med ^ ~(sg * 0x7FFFu);
    const int ch = slice * SLICE_CH + sub8 * 2;
    fx2 res;
    res.x = __uint_as_float(u << 16) + bias[ch];
    res.y = __uint_as_float(u & 0xFFFF0000u) + bias[ch + 1];
    __builtin_nontemporal_store(res, (fx2*)(out + (size_t)node * N_OUT + ch));
  }
}

extern "C" void kernel_launch(void* const* d_in, const int* in_sizes, int n_in,
                              void* d_out, int out_size, void* d_ws, size_t ws_size,
                              hipStream_t stream) {
  const float* x = (const float*)d_in[0];
  const void* ei = d_in[1];  // [2, E]; row = first E; int32 or int64
  const float* W = (const float*)d_in[2];
  const float* b = (const float*)d_in[3];
  float* out = (float*)d_out;

  const int n = in_sizes[0] / N_IN;  // 100000
  const long long E = (long long)n * KNBR;

  unsigned short* h = (unsigned short*)d_ws;             // [4][n][16] u16 keys
  int* e32c = (int*)((char*)d_ws + (size_t)n * 64 * 2);  // [E] int32

  normalize_edges<<<1024, 256, 0, stream>>>(ei, e32c, E);

  const int ntiles = (n + 15) >> 4;     // 6250
  const int waves = (ntiles + 1) >> 1;  // 3125
  const int gblocks = (waves + 4) / 5;  // 625
  gemm_kernel<<<gblocks, 320, 0, stream>>>(x, W, h, n);

  // 8 blocks per chunk (2 sub-blocks x 4 slices); chunk = 64 nodes
  const int chunks = (n + 2 * MB_NODES - 1) / (2 * MB_NODES);  // 1563
  median_kernel<<<chunks * 8, 256, 0, stream>>>(h, e32c, b, out, n);
}

// Round 15
// 69.275 us; speedup vs baseline: 1.5188x; 1.5188x over previous
//
#include <hip/hip_runtime.h>
#include <hip/hip_bf16.h>

#define N_IN 128
#define N_OUT 64
#define KNBR 32

typedef __attribute__((ext_vector_type(4))) float fx4;
typedef __attribute__((ext_vector_type(2))) float fx2;
typedef __attribute__((ext_vector_type(8))) short bh8;

// ---------- compile-time Batcher odd-even mergesort network for 16 ----------
struct Net {
  int a[64];
  int b[64];
  int n;
};

constexpr Net make_batcher16() {
  Net net{};
  net.n = 0;
  const int n = 16;
  for (int p = 1; p < n; p <<= 1)
    for (int k = p; k >= 1; k >>= 1)
      for (int j = k % p; j + k < n; j += 2 * k)
        for (int i = 0; i < k && i + j + k < n; ++i)
          if ((i + j) / (2 * p) == (i + j + k) / (2 * p)) {
            net.a[net.n] = i + j;
            net.b[net.n] = i + j + k;
            net.n++;
          }
  return net;
}

constexpr Net NET16 = make_batcher16();
static_assert(NET16.n == 63, "batcher16 comparator count must be 63");

// packed 16-bit unsigned min/max (VOP3P) — one instr covers 2 channels
__device__ __forceinline__ unsigned pkmin(unsigned a, unsigned b) {
  unsigned r;
  asm("v_pk_min_u16 %0, %1, %2" : "=v"(r) : "v"(a), "v"(b));
  return r;
}
__device__ __forceinline__ unsigned pkmax(unsigned a, unsigned b) {
  unsigned r;
  asm("v_pk_max_u16 %0, %1, %2" : "=v"(r) : "v"(a), "v"(b));
  return r;
}
__device__ __forceinline__ void casp(unsigned& x, unsigned& y) {
  unsigned lo = pkmin(x, y);
  unsigned hi = pkmax(x, y);
  x = lo;
  y = hi;
}

__device__ __forceinline__ unsigned short bf_bits(float f) {
  union { __hip_bfloat16 b; unsigned short u; } cv;
  cv.b = __float2bfloat16(f);  // RNE
  return cv.u;
}

__device__ __forceinline__ unsigned cvtpk(float a, float b) {
  unsigned r;
  asm("v_cvt_pk_bf16_f32 %0, %1, %2" : "=v"(r) : "v"(a), "v"(b));
  return r;
}

// ---------------- kernel 1: h = x @ W via MFMA, stored as bf16 keys ----------
// ONE 16-row tile per wave (6250 waves): 2x the waves of the 2-tile version
// for latency hiding. A/B frags share the same (lane-group,elem)->k mapping
// (permutation cancels). C/D layout: col=lane&15, row=(lane>>4)*4+reg.
__device__ __forceinline__ void tile_compute_store(
    const fx4* xp, const bh8 bf[4][4], unsigned short* __restrict__ h,
    int t, int n, int l4, int g) {
  fx4 acc[4];
#pragma unroll
  for (int ct = 0; ct < 4; ++ct) acc[ct] = fx4{0.f, 0.f, 0.f, 0.f};

#pragma unroll
  for (int kc = 0; kc < 4; ++kc) {
    union { unsigned u[4]; bh8 s; } av;
    // elems j=0..7 <-> k = kc*32 + g*8 + j (same order as B frags)
    av.u[0] = cvtpk(xp[kc * 2 + 0].x, xp[kc * 2 + 0].y);
    av.u[1] = cvtpk(xp[kc * 2 + 0].z, xp[kc * 2 + 0].w);
    av.u[2] = cvtpk(xp[kc * 2 + 1].x, xp[kc * 2 + 1].y);
    av.u[3] = cvtpk(xp[kc * 2 + 1].z, xp[kc * 2 + 1].w);
#pragma unroll
    for (int ct = 0; ct < 4; ++ct)
      acc[ct] = __builtin_amdgcn_mfma_f32_16x16x32_bf16(av.s, bf[kc][ct],
                                                        acc[ct], 0, 0, 0);
  }

#pragma unroll
  for (int ct = 0; ct < 4; ++ct)
#pragma unroll
    for (int r = 0; r < 4; ++r) {
      int row = t * 16 + g * 4 + r;
      if (row < n) {
        unsigned short ub = bf_bits(acc[ct][r]);
        unsigned short key = (ub & 0x8000) ? (unsigned short)(~ub)
                                           : (unsigned short)(ub | 0x8000);
        h[(size_t)row * N_OUT + ct * 16 + l4] = key;
      }
    }
}

__device__ __forceinline__ void tile_load(fx4* xp, const float* __restrict__ x,
                                          int t, int n, int l4, int g) {
  int row = t * 16 + l4;
  if (row >= n) row = n - 1;  // safe clamp (store guard discards)
  const float* xr = x + (size_t)row * N_IN + g * 8;
#pragma unroll
  for (int kc = 0; kc < 4; ++kc) {
    xp[kc * 2 + 0] = *(const fx4*)(xr + kc * 32);
    xp[kc * 2 + 1] = *(const fx4*)(xr + kc * 32 + 4);
  }
}

__global__ __launch_bounds__(320) void gemm_kernel(
    const float* __restrict__ x, const float* __restrict__ W,
    unsigned short* __restrict__ h, int n) {
  const int lane = threadIdx.x & 63;
  const int l4 = lane & 15;
  const int g = lane >> 4;
  const int wid = blockIdx.x * 5 + (threadIdx.x >> 6);
  const int nw = gridDim.x * 5;
  const int ntiles = (n + 15) >> 4;
  if (wid >= ntiles) return;

  // issue this tile's 8 dwordx4 x-loads before the W-frag build (in flight
  // under the 128 W loads)
  fx4 xa[8];
  tile_load(xa, x, wid, n, l4, g);

  // B fragments: elems j=0..7 <-> k = kc*32 + g*8 + j, col = ct*16 + l4
  bh8 bf[4][4];
#pragma unroll
  for (int kc = 0; kc < 4; ++kc)
#pragma unroll
    for (int ct = 0; ct < 4; ++ct) {
      float f[8];
#pragma unroll
      for (int j = 0; j < 8; ++j)
        f[j] = W[(size_t)(kc * 32 + g * 8 + j) * N_OUT + ct * 16 + l4];
      union { unsigned u[4]; bh8 s; } cv;
      cv.u[0] = cvtpk(f[0], f[1]);
      cv.u[1] = cvtpk(f[2], f[3]);
      cv.u[2] = cvtpk(f[4], f[5]);
      cv.u[3] = cvtpk(f[6], f[7]);
      bf[kc][ct] = cv.s;
    }

  tile_compute_store(xa, bf, h, wid, n, l4, g);

  // generic tail (not taken when grid covers ntiles exactly)
  for (int t = wid + nw; t < ntiles; t += nw) {
    tile_load(xa, x, t, n, l4, g);
    tile_compute_store(xa, bf, h, t, n, l4, g);
  }
}

// -------- kernel 2: 2 nodes/wave, 2 channels/lane, packed-u16 exact median --
// (round-8 proven kernel, verbatim: 52.4 us, FETCH 149 MB at ~2.9 TB/s —
// measured floor for the random-row gather: r13 showed more MLP doesn't
// raise the rate; r9/r14 showed smaller rows trade misses for 4x the
// line-touches and lose. 128B-row = 1 line/touch is the minimum shape.)
__global__ __launch_bounds__(256, 4) void median_kernel(
    const unsigned short* __restrict__ h, const void* __restrict__ ei,
    const float* __restrict__ bias, float* __restrict__ out, int n) {
  const int lane = threadIdx.x & 63;
  const int wid = blockIdx.x * (blockDim.x >> 6) + (threadIdx.x >> 6);
  const int nodeA = wid * 2;
  if (nodeA >= n) return;
  const int l5 = lane & 31;
  const int mynode = nodeA + (lane >> 5);  // half 0 -> A, half 1 -> B

  const int* e32 = (const int*)ei;
  const long long* e64 = (const long long*)ei;
  // int64 little-endian => high words (odd int32 slots) of first 8 elems are 0
  bool is64 = (e32[1] == 0) && (e32[3] == 0) && (e32[5] == 0) &&
              (e32[7] == 0) && (e32[9] == 0) && (e32[11] == 0) &&
              (e32[13] == 0) && (e32[15] == 0);

  // lane l5 of each half holds neighbor l5 of its node (coalesced, nt)
  int idx;
  if (is64) {
    idx = (int)__builtin_nontemporal_load(&e64[mynode * KNBR + l5]);
  } else {
    idx = __builtin_nontemporal_load(&e32[mynode * KNBR + l5]);
  }

  const unsigned laneoff = (unsigned)l5 * 4u;  // dword (2 ch) within 128B row
  unsigned v[33];
#pragma unroll
  for (int j = 0; j < 32; ++j) {
    // broadcast lane j's index within each 32-lane half (ds_bpermute, LGKM)
    int s = __shfl(idx, j, 32);
    unsigned off = ((unsigned)s << 7) + laneoff;
    v[j] = *(const unsigned*)((const char*)h + off);
  }
  {
    unsigned off = ((unsigned)mynode << 7) + laneoff;  // self loop
    v[32] = *(const unsigned*)((const char*)h + off);
  }

  // sort the two 16-element halves (packed: both channels at once)
#pragma unroll
  for (int t = 0; t < NET16.n; ++t) casp(v[NET16.a[t]], v[NET16.b[t]]);
#pragma unroll
  for (int t = 0; t < NET16.n; ++t) casp(v[16 + NET16.a[t]], v[16 + NET16.b[t]]);

  // ranks 15,16 of merged 32 via crossing min/max
  unsigned r15 = 0u;           // smallest key
  unsigned r16 = 0xFFFFFFFFu;  // largest key (per packed half)
#pragma unroll
  for (int i = 0; i < 16; ++i) {
    unsigned lo = pkmin(v[i], v[16 + 15 - i]);
    unsigned hi = pkmax(v[i], v[16 + 15 - i]);
    r15 = pkmax(r15, lo);
    r16 = pkmin(r16, hi);
  }

  // median of 33 = clamp(self, r15, r16) in key domain (exact)
  unsigned med = pkmax(r15, pkmin(v[32], r16));

  // inverse transform (per 16-bit half): t>=0x8000 ? t^0x8000 : ~t
  unsigned sg = (med >> 15) & 0x00010001u;
  unsigned u = med ^ ~(sg * 0x7FFFu);
  fx2 res;
  res.x = __uint_as_float(u << 16) + bias[2 * l5];              // channel 2*l5
  res.y = __uint_as_float(u & 0xFFFF0000u) + bias[2 * l5 + 1];  // ch 2*l5+1
  // nt store: out is write-once — don't evict h from L2
  __builtin_nontemporal_store(res, (fx2*)(out + (size_t)mynode * N_OUT + 2 * l5));
}

extern "C" void kernel_launch(void* const* d_in, const int* in_sizes, int n_in,
                              void* d_out, int out_size, void* d_ws, size_t ws_size,
                              hipStream_t stream) {
  const float* x = (const float*)d_in[0];
  const void* ei = d_in[1];  // [2, E]; row = first E; int32 or int64
  const float* W = (const float*)d_in[2];
  const float* b = (const float*)d_in[3];
  float* out = (float*)d_out;
  unsigned short* h = (unsigned short*)d_ws;  // [n, 64] transformed bf16 keys

  const int n = in_sizes[0] / N_IN;  // 100000

  const int ntiles = (n + 15) >> 4;      // 6250
  const int gblocks = (ntiles + 4) / 5;  // 1250 blocks of 5 waves, 1 tile/wave
  gemm_kernel<<<gblocks, 320, 0, stream>>>(x, W, h, n);

  // 2 nodes per wave, 4 waves per block
  const int grid = (n + 7) / 8;
  median_kernel<<<grid, 256, 0, stream>>>(h, ei, b, out, n);
}